// Round 13
// baseline (625.639 us; speedup 1.0000x reference)
//
#include <hip/hip_runtime.h>

// Problem constants: B=N=256, D=S=1024
// out = [ctx 256*1024 fp32 ; W 256*256*1024 fp32]

typedef _Float16 half8 __attribute__((ext_vector_type(8)));
typedef _Float16 half4 __attribute__((ext_vector_type(4)));
typedef float floatx16 __attribute__((ext_vector_type(16)));

static __device__ __forceinline__ void split_f32(float x, _Float16& hi, _Float16& lo) {
    _Float16 h = (_Float16)x;
    hi = h;
    lo = (_Float16)(x - (float)h);
}

// ---------------------------------------------------------------------------
// GEMM body (proven): C[M,N] (+)= A[M,K-slice] @ B, fp32 in, hi/lo fp16 split
// on BOTH operands (3 MFMAs). Tile 64x64, 256 threads, BK=32.
// SPLITK: atomicAdd epilogue over grid.z K-slices.
// ---------------------------------------------------------------------------
template <bool BT, bool SPLITK>
__device__ __forceinline__ void gemm_body(
    const float* __restrict__ Ag, const float* __restrict__ Bg,
    float* __restrict__ Cf, int Kdim, int Ndim, int KC, int bx, int by, int bz)
{
    __shared__ __align__(16) _Float16 AsHi[4 * 64 * 8];
    __shared__ __align__(16) _Float16 AsLo[4 * 64 * 8];
    __shared__ __align__(16) _Float16 BsHi[4 * 64 * 8];
    __shared__ __align__(16) _Float16 BsLo[4 * 64 * 8];

    const int tid  = threadIdx.x;
    const int lane = tid & 63;
    const int wave = tid >> 6;
    const int wy = wave >> 1, wx = wave & 1;
    const int l31 = lane & 31, l5 = lane >> 5;
    const int m0 = by * 64, n0 = bx * 64;
    const int kt0 = (bz * KC) >> 5;

    floatx16 acc;
#pragma unroll
    for (int j = 0; j < 16; ++j) acc[j] = 0.0f;

    const int sA_m  = tid >> 2;
    const int sA_kg = tid & 3;
    const int sB_n  = tid & 63;
    const int sB_kg = tid >> 6;

    const int nkt = KC / 32;
#pragma unroll 1
    for (int kt2 = 0; kt2 < nkt; ++kt2) {
        const int kt = kt0 + kt2;
        __syncthreads();
        {
            const float* src = Ag + (size_t)(m0 + sA_m) * Kdim + kt * 32 + sA_kg * 8;
            half8 hi, lo;
#pragma unroll
            for (int j = 0; j < 8; ++j) {
                _Float16 h, l;
                split_f32(src[j], h, l);
                hi[j] = h; lo[j] = l;
            }
            *(half8*)&AsHi[(sA_kg * 64 + sA_m) * 8] = hi;
            *(half8*)&AsLo[(sA_kg * 64 + sA_m) * 8] = lo;
        }
        if constexpr (BT) {
            const float* src = Bg + (size_t)(n0 + sA_m) * Kdim + kt * 32 + sA_kg * 8;
            half8 hi, lo;
#pragma unroll
            for (int j = 0; j < 8; ++j) {
                _Float16 h, l;
                split_f32(src[j], h, l);
                hi[j] = h; lo[j] = l;
            }
            *(half8*)&BsHi[(sA_kg * 64 + sA_m) * 8] = hi;
            *(half8*)&BsLo[(sA_kg * 64 + sA_m) * 8] = lo;
        } else {
            const float* src = Bg + (size_t)(kt * 32 + sB_kg * 8) * Ndim + n0 + sB_n;
            half8 hi, lo;
#pragma unroll
            for (int j = 0; j < 8; ++j) {
                _Float16 h, l;
                split_f32(src[(size_t)j * Ndim], h, l);
                hi[j] = h; lo[j] = l;
            }
            *(half8*)&BsHi[(sB_kg * 64 + sB_n) * 8] = hi;
            *(half8*)&BsLo[(sB_kg * 64 + sB_n) * 8] = lo;
        }
        __syncthreads();
#pragma unroll
        for (int ks = 0; ks < 2; ++ks) {
            const int kg = ks * 2 + l5;
            const half8 ah = *(half8*)&AsHi[(kg * 64 + wy * 32 + l31) * 8];
            const half8 al = *(half8*)&AsLo[(kg * 64 + wy * 32 + l31) * 8];
            const half8 bh = *(half8*)&BsHi[(kg * 64 + wx * 32 + l31) * 8];
            const half8 bl = *(half8*)&BsLo[(kg * 64 + wx * 32 + l31) * 8];
            acc = __builtin_amdgcn_mfma_f32_32x32x16_f16(ah, bh, acc, 0, 0, 0);
            acc = __builtin_amdgcn_mfma_f32_32x32x16_f16(ah, bl, acc, 0, 0, 0);
            acc = __builtin_amdgcn_mfma_f32_32x32x16_f16(al, bh, acc, 0, 0, 0);
        }
    }

    // C/D layout (verified): col = lane&31, row = (reg&3) + 8*(reg>>2) + 4*(lane>>5)
#pragma unroll
    for (int reg = 0; reg < 16; ++reg) {
        const int row = m0 + wy * 32 + (reg & 3) + 8 * (reg >> 2) + 4 * l5;
        const int col = n0 + wx * 32 + l31;
        if constexpr (SPLITK) atomicAdd(&Cf[(size_t)row * Ndim + col], acc[reg]);
        else                  Cf[(size_t)row * Ndim + col] = acc[reg];
    }
}

template <bool BT>
__global__ __launch_bounds__(256, 2) void gemm_splitk(
    const float* __restrict__ Ag, const float* __restrict__ Bg,
    float* __restrict__ Cf, int Kdim, int Ndim, int KC)
{
    gemm_body<BT, true>(Ag, Bg, Cf, Kdim, Ndim, KC,
                        blockIdx.x, blockIdx.y, blockIdx.z);
}

// ---------------------------------------------------------------------------
// Layout-preserving fp32 -> fp16 copy of FV (NOT a transpose; R9's staging
// request shape is kept). Each (i, tile, z) block-slice copies 8 KB fp32 ->
// 4 KB fp16, fully coalesced (float4 reads, half4 writes).
// ---------------------------------------------------------------------------
__device__ __forceinline__ void fv16_copy_body(
    const float* __restrict__ FV, _Float16* __restrict__ T, int i, int tile, int z)
{
    const size_t base = (size_t)i * 262144 + (size_t)tile * 16384 + (size_t)z * 2048;
    const float* src = FV + base;
    _Float16* dst = T + base;
    const int tid = threadIdx.x;  // 256
#pragma unroll
    for (int j = 0; j < 2; ++j) {
        const float4 v = *(const float4*)(src + (size_t)(j * 256 + tid) * 4);
        half4 h;
        h[0] = (_Float16)v.x; h[1] = (_Float16)v.y;
        h[2] = (_Float16)v.z; h[3] = (_Float16)v.w;
        *(half4*)(dst + (size_t)(j * 256 + tid) * 4) = h;
    }
}

// Combined dispatch: gemm1 split-K (y<4, 512 blocks, machine-filling) + FV
// fp16 copy (y>=4, 32768 slices) run concurrently; copy delivery (~402 MB)
// overlaps gemm1's tail.
__global__ __launch_bounds__(256, 2) void gemm1_plus_copy(
    const float* __restrict__ state, const float* __restrict__ Q,
    float* __restrict__ A1,
    const float* __restrict__ FV, _Float16* __restrict__ T)
{
    if (blockIdx.y < 4)
        gemm_body<true, true>(state, Q, A1, 1024, 1024, 128,
                              blockIdx.x, blockIdx.y, blockIdx.z);
    else
        fv16_copy_body(FV, T, blockIdx.y - 4, blockIdx.x, blockIdx.z);
}

// Bank swizzle for Bs (proven R9): XOR bits[6:4] with bits[9:7]. Involution;
// applied identically on store and read, so placement is self-consistent.
static __device__ __forceinline__ int bs_swz(int byte_off) {
    return byte_off ^ (((byte_off >> 7) & 7) << 4);
}

// ---------------------------------------------------------------------------
// Fused R13 = R9 structure (best, 255 us) with FV in fp16.
// DELIVERY MODEL (closes to 1%): R9 delivers 4x268 MB multicast staging +
// 268 MB epilogue re-read + 268 MB W = 1.6 GB in 255 us = 6.27 TB/s = the
// measured copy ceiling (m13: 6.29). The kernel is delivery-bound; HBM
// counters (2.1 TB/s) hid the L2-multicast share. fp16 FV halves every
// read term: 4x134 + 134 + 268 = 938 MB -> floor ~149 us.
// Staging keeps R9's exact request shape: half4 loads (coalesced 512 B per
// wave-instr), same in-register 8x4 transpose, same half8 b128 LDS stores
// via bs_swz. No conversion VALU (values already fp16). Epilogue fv reads
// fp16 (R5-proven accurate). Stagger reverted (R12: -8 us, delivery-neutral).
// ---------------------------------------------------------------------------
__global__ __launch_bounds__(512, 2) void fused_attn(
    const _Float16* __restrict__ FV16, const float* __restrict__ Mf,
    float* __restrict__ ctx, float* __restrict__ Wout)
{
    __shared__ __align__(16) _Float16 AsHi[2 * 64 * 8];
    __shared__ __align__(16) _Float16 AsLo[2 * 64 * 8];
    __shared__ __align__(16) _Float16 Bs[2 * 1024 * 8];
    __shared__ __align__(16) float red1[64 * 4];
    __shared__ __align__(16) float red2[64 * 4];

    const int tid  = threadIdx.x;
    const int lane = tid & 63;
    const int wave = tid >> 6;
    const int wx = wave & 3;   // d-slice (256 cols)
    const int wy = wave >> 2;  // m-half (32 rows)
    const int l31 = lane & 31, l5 = lane >> 5;

    // XCD-aware swizzle: all 4 bt of an i share one XCD.
    const int w   = blockIdx.x;   // 0..1023
    const int xcd = w & 7;
    const int k   = w >> 3;       // 0..127
    const int i   = (xcd << 5) + (k >> 2);  // 0..255
    const int bt  = k & 3;                  // 0..3

    const _Float16* __restrict__ Fi = FV16 + (size_t)i * 262144;

    floatx16 acc[8];
#pragma unroll
    for (int nt = 0; nt < 8; ++nt)
#pragma unroll
        for (int j = 0; j < 16; ++j) acc[nt][j] = 0.0f;

    const int am = tid >> 1, akg = tid & 1;  // A staging (tid < 128)

    // B staging mapping (R9): thread owns n-subgroup n8 = tid>>8 (8 rows) and
    // cols [c0, c0+4), c0 = (tid&255)*4. 8x half4 (8 B) loads per chunk.
    const int n8 = tid >> 8;
    const int c0 = (tid & 255) * 4;

    // ---- prefetch chunk 0 into registers ----
    half4 pv[8];
    float4 pa0, pa1;
    {
        const _Float16* src = Fi + (size_t)(n8 * 8) * 1024 + c0;
#pragma unroll
        for (int r = 0; r < 8; ++r) pv[r] = *(const half4*)(src + (size_t)r * 1024);
    }
    if (tid < 128) {
        const float* ap = Mf + (size_t)(bt * 64 + am) * 256 + akg * 8;
        pa0 = *(const float4*)(ap);
        pa1 = *(const float4*)(ap + 4);
    }

#pragma unroll 1
    for (int kt = 0; kt < 16; ++kt) {
        __syncthreads();  // drains prefetch (issued a full compute-phase ago)
        // ---- store staged chunk to LDS (fp32 M split to hi/lo here) ----
        if (tid < 128) {
            half8 hi, lo;
#pragma unroll
            for (int j = 0; j < 4; ++j) {
                _Float16 h, l;
                split_f32((&pa0.x)[j], h, l);
                hi[j] = h; lo[j] = l;
            }
#pragma unroll
            for (int j = 0; j < 4; ++j) {
                _Float16 h, l;
                split_f32((&pa1.x)[j], h, l);
                hi[4 + j] = h; lo[4 + j] = l;
            }
            *(half8*)&AsHi[(akg * 64 + am) * 8] = hi;
            *(half8*)&AsLo[(akg * 64 + am) * 8] = lo;
        }
        // B: in-register 8x4 transpose -> 4 half8 b128 stores (swizzled banks)
#pragma unroll
        for (int j = 0; j < 4; ++j) {
            half8 h;
#pragma unroll
            for (int r = 0; r < 8; ++r) h[r] = pv[r][j];
            const int byte_off = (n8 * 1024 + c0 + j) * 16;
            *(half8*)((char*)Bs + bs_swz(byte_off)) = h;
        }
        __syncthreads();
        // ---- prefetch next chunk (overlaps with compute below) ----
        if (kt + 1 < 16) {
            const _Float16* src = Fi + (size_t)((kt + 1) * 16 + n8 * 8) * 1024 + c0;
#pragma unroll
            for (int r = 0; r < 8; ++r) pv[r] = *(const half4*)(src + (size_t)r * 1024);
            if (tid < 128) {
                const float* ap = Mf + (size_t)(bt * 64 + am) * 256 + (kt + 1) * 16 + akg * 8;
                pa0 = *(const float4*)(ap);
                pa1 = *(const float4*)(ap + 4);
            }
        }
        // ---- compute: 8 n-tiles x (hi,lo) MFMA ----
        const half8 ah = *(half8*)&AsHi[(l5 * 64 + wy * 32 + l31) * 8];
        const half8 al = *(half8*)&AsLo[(l5 * 64 + wy * 32 + l31) * 8];
#pragma unroll
        for (int nt = 0; nt < 8; ++nt) {
            const int byte_off = (l5 * 1024 + wx * 256 + nt * 32 + l31) * 16;
            const half8 b = *(const half8*)((const char*)Bs + bs_swz(byte_off));
            acc[nt] = __builtin_amdgcn_mfma_f32_32x32x16_f16(ah, b, acc[nt], 0, 0, 0);
            acc[nt] = __builtin_amdgcn_mfma_f32_32x32x16_f16(al, b, acc[nt], 0, 0, 0);
        }
    }

    // ---- softmax over d (rows span 4 wx waves) ----
    // lane holds: col = wx*256 + nt*32 + l31 ; row = wy*32 + (reg&3)+8*(reg>>2)+4*l5
    float st[16];
#pragma unroll
    for (int reg = 0; reg < 16; ++reg) {
        float v = acc[0][reg];
#pragma unroll
        for (int nt = 1; nt < 8; ++nt) v = fmaxf(v, acc[nt][reg]);
#pragma unroll
        for (int off = 1; off < 32; off <<= 1) v = fmaxf(v, __shfl_xor(v, off));
        st[reg] = v;
    }
    if (l31 == 0) {
#pragma unroll
        for (int reg = 0; reg < 16; ++reg) {
            const int row = wy * 32 + (reg & 3) + 8 * (reg >> 2) + 4 * l5;
            red1[row * 4 + wx] = st[reg];
        }
    }
    __syncthreads();
    float rmax[16];
#pragma unroll
    for (int reg = 0; reg < 16; ++reg) {
        const int row = wy * 32 + (reg & 3) + 8 * (reg >> 2) + 4 * l5;
        const float4 m4 = *(const float4*)&red1[row * 4];
        rmax[reg] = fmaxf(fmaxf(m4.x, m4.y), fmaxf(m4.z, m4.w));
    }
#pragma unroll
    for (int reg = 0; reg < 16; ++reg) {
        float s = 0.0f;
#pragma unroll
        for (int nt = 0; nt < 8; ++nt) {
            const float p = __expf(acc[nt][reg] - rmax[reg]);
            acc[nt][reg] = p;
            s += p;
        }
#pragma unroll
        for (int off = 1; off < 32; off <<= 1) s += __shfl_xor(s, off);
        st[reg] = s;
    }
    if (l31 == 0) {
#pragma unroll
        for (int reg = 0; reg < 16; ++reg) {
            const int row = wy * 32 + (reg & 3) + 8 * (reg >> 2) + 4 * l5;
            red2[row * 4 + wx] = st[reg];
        }
    }
    __syncthreads();
    float inv[16];
#pragma unroll
    for (int reg = 0; reg < 16; ++reg) {
        const int row = wy * 32 + (reg & 3) + 8 * (reg >> 2) + 4 * l5;
        const float4 s4 = *(const float4*)&red2[row * 4];
        inv[reg] = 1.0f / (s4.x + s4.y + s4.z + s4.w);
    }

    // ---- write W, accumulate context (fv from fp16 FV, halves delivery) ----
    float csum[8];
#pragma unroll
    for (int nt = 0; nt < 8; ++nt) csum[nt] = 0.0f;

    const int rowbase = bt * 64 + wy * 32;
#pragma unroll
    for (int nt = 0; nt < 8; ++nt) {
        const int col = wx * 256 + nt * 32 + l31;
#pragma unroll
        for (int reg = 0; reg < 16; ++reg) {
            const int row = (reg & 3) + 8 * (reg >> 2) + 4 * l5;
            const float wv = acc[nt][reg] * inv[reg];
            Wout[((size_t)(i * 256 + rowbase + row)) * 1024 + col] = wv;
            const float fv = (float)Fi[(size_t)(rowbase + row) * 1024 + col];
            csum[nt] += wv * fv;
        }
    }
#pragma unroll
    for (int nt = 0; nt < 8; ++nt) {
        const float v = csum[nt] + __shfl_xor(csum[nt], 32);
        if (l5 == 0)
            atomicAdd(&ctx[(size_t)i * 1024 + wx * 256 + nt * 32 + l31], v);
    }
}

// ---------------------------------------------------------------------------
extern "C" void kernel_launch(void* const* d_in, const int* in_sizes, int n_in,
                              void* d_out, int out_size, void* d_ws, size_t ws_size,
                              hipStream_t stream)
{
    const float* FV    = (const float*)d_in[0];  // [256,256,1024]
    const float* state = (const float*)d_in[1];  // [256,1024]
    const float* Q     = (const float*)d_in[2];  // [1024,1024]
    const float* Km    = (const float*)d_in[3];  // [1024,256]

    float* out = (float*)d_out;
    float* ctx = out;                 // [256,1024]
    float* W   = out + 256 * 1024;    // [256,256,1024]

    char* ws = (char*)d_ws;
    float*    A1 = (float*)ws;                               // [256,1024] fp32, 1 MB
    float*    Mf = (float*)(ws + (1 << 20));                 // [256,256]  fp32, 256 KB
    _Float16* T  = (_Float16*)(ws + (1 << 20) + (1 << 18));  // [256,256,1024] f16, 134 MB

    // split-K accumulators (A1, Mf) + ctx atomics -> zero
    (void)hipMemsetAsync(ws, 0, (1 << 20) + (1 << 18), stream);
    (void)hipMemsetAsync(ctx, 0, 256 * 1024 * sizeof(float), stream);

    // gemm1 split-K (512 blocks) concurrent with FV fp32->fp16 copy
    gemm1_plus_copy<<<dim3(16, 260, 8), 256, 0, stream>>>(state, Q, A1, FV, T);

    // M = A1 @ K  (B stored [K,N]), split-K x16
    gemm_splitk<false><<<dim3(4, 4, 16), 256, 0, stream>>>(
        A1, Km, Mf, 1024, 256, 64);

    // fused logits -> softmax -> W + ctx (R9 structure, fp16 FV delivery)
    fused_attn<<<dim3(1024), 512, 0, stream>>>(T, Mf, ctx, W);
}